// Round 21
// baseline (85.994 us; speedup 1.0000x reference)
//
#include <hip/hip_runtime.h>
#include <math.h>

// ScoreNet: B=8, NV=512, C=256, H=6, R=32, PAIR_H=16, RBF_K=8
// R21: k_gp occupancy 3->4 blocks/CU (__launch_bounds__(256,4), 16 waves/CU).
//   Enabler: phase-2 chunks processed SEQUENTIALLY (A: MFMA+reduce, then B)
//   with sched_barrier(0) between -> peak D-liveness 64->32 regs, est. peak
//   ~110 < 128 cap (R16 lesson: >cap => catastrophic scratch spill; watch
//   FETCH_SIZE). R11's sequential null was at fixed occupancy; here it buys
//   +33% TLP on the latency-limited phase. Everything else = R20.

#define UK 224

typedef __attribute__((ext_vector_type(8)))  short short8;
typedef __attribute__((ext_vector_type(16))) float f32x16;
typedef __attribute__((ext_vector_type(4)))  int   int4v;

__device__ __forceinline__ float sigmoidf_(float x){ return 1.0f/(1.0f + __expf(-x)); }
__device__ __forceinline__ unsigned f2bf(float x){
    unsigned u = __builtin_bit_cast(unsigned, x);
    return (u + 0x7fffu + ((u>>16)&1u)) >> 16;       // RNE f32->bf16
}
__device__ __forceinline__ unsigned pk2(float lo, float hi){
    unsigned r;
    asm("v_cvt_pk_bf16_f32 %0, %1, %2" : "=v"(r) : "v"(lo), "v"(hi));
    return r;
}
__device__ __forceinline__ f32x16 zero16(){
    f32x16 z;
    #pragma unroll
    for (int i = 0; i < 16; i++) z[i] = 0.f;
    return z;
}

// merged: blocks <4096 pool feats -> bf16 xb; blocks >=4096 pack WT (transposed, bf16) + bcat
__global__ __launch_bounds__(256) void k_prep(const float* __restrict__ feats,
        const float* __restrict__ Wq, const float* __restrict__ Wk,
        const float* __restrict__ Wpi, const float* __restrict__ bpi,
        const float* __restrict__ Wpj, const float* __restrict__ bpj,
        const float* __restrict__ dW, const float* __restrict__ db,
        const float* __restrict__ a_pair,
        unsigned short* __restrict__ xb, unsigned short* __restrict__ WT,
        float* __restrict__ bcat){
    int blk = blockIdx.x, tid = threadIdx.x;
    if (blk < 4096){
        int b = blk >> 9, n = blk & 511;
        size_t base = ((size_t)(b*1025 + 1 + 2*n))*256 + tid;
        float v = 0.5f*(feats[base] + feats[base+256]);
        xb[(size_t)blk*256 + tid] = (unsigned short)f2bf(v);
    } else {
        int col = blk - 4096;    // 0..447
        int c   = tid;           // k index 0..255
        const float invSqrtR = 0.17677669529663687f; // 1/sqrt(32)
        float sp = 1.5f*sigmoidf_(a_pair[0]);
        float v;
        if      (col < 192)  v = Wq[c*192 + col]*invSqrtR;
        else if (col < 208)  v = sp*Wpi[c*16 + (col-192)];
        else if (col < 400)  v = Wk[c*192 + (col-208)];
        else if (col < 416)  v = Wpj[c*16 + (col-400)];
        else if (col == 416) v = dW[c];
        else v = 0.f;
        WT[col*256 + c] = (unsigned short)f2bf(v);
        if (tid == 0){
            float bv = 0.f;
            if      (col >= 192 && col < 208) bv = sp*bpi[col-192];
            else if (col >= 400 && col < 416) bv = bpj[col-400];
            else if (col == 416)              bv = db[0];
            bcat[col] = bv;
        }
    }
}

// xb[4096][256] @ WT^T -> routed to Ub/Vb (bf16, [4096][224], zero-padded) + dv
__global__ __launch_bounds__(256) void k_uv(const unsigned short* __restrict__ xb,
        const unsigned short* __restrict__ WT, const float* __restrict__ bcat,
        unsigned short* __restrict__ Ub, unsigned short* __restrict__ Vb,
        float* __restrict__ dv){
    int tid = threadIdx.x;
    int lane = tid & 63, l31 = lane & 31, hf = lane >> 5;
    int w = tid >> 6, wr = w >> 1, wc = w & 1;
    int c0 = blockIdx.x*64, r0 = blockIdx.y*64;
    const unsigned short* ap = xb + (size_t)(r0 + wr*32 + l31)*256 + 8*hf;
    const unsigned short* bp = WT + (size_t)(c0 + wc*32 + l31)*256 + 8*hf;
    f32x16 acc = zero16();
    #pragma unroll 4
    for (int k0 = 0; k0 < 256; k0 += 16){
        short8 a  = *(const short8*)(ap + k0);
        short8 bb = *(const short8*)(bp + k0);
        acc = __builtin_amdgcn_mfma_f32_32x32x16_bf16(a, bb, acc, 0, 0, 0);
    }
    int col = c0 + wc*32 + l31;          // uniform per lane across all 16 accs
    int rb  = r0 + wr*32 + 4*hf;
    float bc = bcat[col];
    #pragma unroll
    for (int r = 0; r < 16; r++){
        int row = rb + (r&3) + 8*(r>>2);
        float v = acc[r] + bc;
        size_t ui = (size_t)row*UK;
        if (col < 208){
            if (col >= 192) v = fmaxf(v, 0.f);        // a_i relu
            Ub[ui + col] = (unsigned short)f2bf(v);
        } else if (col < 224){
            Vb[ui + col-208] = (unsigned short)f2bf(v);
            Ub[ui + col] = 0;                          // Ub K-pad
        } else if (col < 416){
            if (col >= 400) v = fmaxf(v, 0.f);        // b_j relu
            Vb[ui + col-208] = (unsigned short)f2bf(v);
        } else if (col == 416){
            dv[row] = v;
            Vb[ui + 208] = 0;                          // Vb K-pad
        } else if (col < 432){
            Vb[ui + col-208] = 0;                      // Vb K-pad (cols 417..431 are zero-cols)
        }
        // col >= 432: dead padding, skip
    }
}

// FUSED: S_lin (bf16 MFMA, K-split) + pair MLPs + diag + logit scale
// tile: 32 n-rows x 64 m-cols; grid dim3(8,16,8)
__global__ __launch_bounds__(256, 4) void k_gp(const unsigned short* __restrict__ Ub,
        const unsigned short* __restrict__ Vb, const float* __restrict__ xy,
        const float* __restrict__ gW1, const float* __restrict__ gb1,
        const float* __restrict__ gW2, const float* __restrict__ gb2,
        const float* __restrict__ aW1, const float* __restrict__ ab1,
        const float* __restrict__ aW2, const float* __restrict__ ab2,
        const float* __restrict__ dv,
        const float* __restrict__ a_geom, const float* __restrict__ a_ang,
        const float* __restrict__ lsc,
        float* __restrict__ S){
    __shared__ float acc_lds[2][32][64];   // two K-partials, 16 KB
    int tid = threadIdx.x;
    int lane = tid & 63, l31 = lane & 31, hf = lane >> 5;
    int w = tid >> 6, wr = w >> 1, wc = w & 1;   // wr = K-half, wc = m-half
    int b = blockIdx.z;
    int m0 = blockIdx.x*64, n0 = blockIdx.y*32;

    // ---------- phase 1: GEMM tile (K split across wave pairs) ----------
    {
        const unsigned short* ap = Ub + (size_t)(b*512 + n0 + l31)*UK + wr*112 + 8*hf;
        const unsigned short* bp = Vb + (size_t)(b*512 + m0 + wc*32 + l31)*UK + wr*112 + 8*hf;
        f32x16 acc = zero16();
        #pragma unroll
        for (int t = 0; t < 7; t++){
            short8 a  = *(const short8*)(ap + t*16);
            short8 bb = *(const short8*)(bp + t*16);
            acc = __builtin_amdgcn_mfma_f32_32x32x16_bf16(a, bb, acc, 0, 0, 0);
        }
        int colL = wc*32 + l31;
        #pragma unroll
        for (int r = 0; r < 16; r++)
            acc_lds[wr][(r&3) + 8*(r>>2) + 4*hf][colL] = acc[r];
    }
    __syncthreads();

    // ---------- pair-MLP setup (weights/tables) ----------
    float sg = 1.5f*sigmoidf_(a_geom[0]);
    float sa = 1.5f*sigmoidf_(a_ang[0]);
    float ls = 0.5f + 2.5f*sigmoidf_(lsc[0]);

    short8 wg, wa;
    #pragma unroll
    for (int j = 0; j < 8; j++){
        int f = hf*8 + j;
        float vg = (f < 12) ? gW1[f*32 + l31] : 0.f;
        float va = (f >= 10 && l31 < 16) ? aW1[(f-10)*16 + l31] : 0.f;
        wg[j] = (short)f2bf(vg);
        wa[j] = (short)f2bf(va);
    }
    // geom tables: all 16 regs; angle tables: only r=0..7 have h<16
    float nbg[16], g2g[16], nba[8], g2a[8];
    float bsum = 0.f;
    #pragma unroll
    for (int r = 0; r < 16; r++){
        int h = (r&3) + 8*(r>>2) + 4*hf;
        float bg  = gb1[h];
        float wg2 = sg*gW2[h];
        nbg[r] = -bg; g2g[r] = wg2; bsum += bg*wg2;
        if (r < 8){   // h<16 exactly when r<8 (both halves)
            float ba  = ab1[h];
            float wa2 = sa*aW2[h];
            nba[r] = -ba; g2a[r] = wa2; bsum += ba*wa2;
        }
    }
    bsum += __shfl_xor(bsum, 32);
    float cb = sg*gb2[0] + sa*ab2[0] + bsum;

    const float GAMMA = 12.2499985f;    // 1/(2*spacing^2 + 1e-8)
    const float TWOGD = 4.9497469f;     // 2*GAMMA*spacing
    const float* xyb = xy + (size_t)b*1024;

    // ---------- phase 2: pair MLPs for 8 tile rows per wave ----------
    int m_w = m0 + lane;                // this lane's own pair column (dedup)
    float2 pmv = *(const float2*)(xyb + 2*m_w);
    float ym = pmv.x, xm = pmv.y;
    bool padm = (fabsf(ym) < 1e-9f) && (fabsf(xm) < 1e-9f);

    for (int i = 0; i < 8; i++){
        int nrow = (w << 3) + i;        // tile-local row, wave-uniform
        int nn = n0 + nrow;
        float yn = xyb[2*nn], xn = xyb[2*nn+1];
        bool padn = (fabsf(yn) < 1e-9f) && (fabsf(xn) < 1e-9f);
        float msk = (padn || padm) ? 0.f : 1.f;

        float dy = yn - ym, dx = xn - xm;
        float r2 = dy*dy + dx*dx;
        float re = sqrtf(r2 + 1e-8f);
        float c1, s1;
        if (r2 > 0.f){ float inv = rsqrtf(r2); c1 = dx*inv; s1 = dy*inv; }
        else { c1 = 1.f; s1 = 0.f; }    // atan2(0,0)=0
        float c2 = c1*c1 - s1*s1, s2 = 2.f*c1*s1;
        float c4 = c2*c2 - s2*s2, s4 = 2.f*c2*s2;
        float e0 = __expf(-GAMMA*(r2 + 1e-8f));
        float E  = __expf(TWOGD*re);
        float u  = e0;
        float p0 = u;
        u *= E; float p1 = 0.60653066f*u;
        u *= E; float p2 = 0.13533528f*u;
        u *= E; float p3 = 0.011108997f*u;
        u *= E; float p4 = 3.3546263e-4f*u;
        u *= E; float p5 = 3.7266532e-6f*u;
        u *= E; float p6 = 1.5229979e-8f*u;
        u *= E; float p7 = 2.2897348e-11f*u;
        unsigned pk0 = pk2(dy, dx), pk1 = pk2(p0, p1), pk2_ = pk2(p2, p3), pk3 = pk2(p4, p5);
        unsigned pk4 = pk2(p6, p7), pk5 = pk2(c1, s1), pk6 = pk2(c2, s2), pk7 = pk2(c4, s4);

        // exchange partner k-halves (selection evaluated in SOURCE lane)
        int s0 = __shfl_xor((int)(hf ? pk0 : pk4), 32);
        int s1i= __shfl_xor((int)(hf ? pk1 : pk5), 32);
        int s2i= __shfl_xor((int)(hf ? pk2_: pk6), 32);
        int s3i= __shfl_xor((int)(hf ? pk3 : pk7), 32);

        // ---- chunk A: MFMA + reduce, fully retired before chunk B ----
        float accA, accB;
        {
            int fA0 = hf ? s0 : (int)pk0, fA1 = hf ? s1i : (int)pk1;
            int fA2 = hf ? s2i : (int)pk2_, fA3 = hf ? s3i : (int)pk3;
            int4v ivA = {fA0, fA1, fA2, fA3};
            short8 bfA = __builtin_bit_cast(short8, ivA);
            f32x16 z = zero16();
            f32x16 dgA = __builtin_amdgcn_mfma_f32_32x32x16_bf16(wg, bfA, z, 0, 0, 0);
            f32x16 daA = __builtin_amdgcn_mfma_f32_32x32x16_bf16(wa, bfA, z, 0, 0, 0);
            float a0=0.f,a1=0.f,a2=0.f;
            #pragma unroll
            for (int r = 0; r < 8; r++){
                a0 += fmaxf(dgA[r],   nbg[r])   * g2g[r];
                a1 += fmaxf(dgA[r+8], nbg[r+8]) * g2g[r+8];
                a2 += fmaxf(daA[r],   nba[r])   * g2a[r];
            }
            accA = (a0 + a1) + a2;
        }
        __builtin_amdgcn_sched_barrier(0);   // keep chunk-B MFMAs below (liveness cap)
        // ---- chunk B ----
        {
            int fB0 = hf ? (int)pk4 : s0,  fB1 = hf ? (int)pk5 : s1i;
            int fB2 = hf ? (int)pk6 : s2i, fB3 = hf ? (int)pk7 : s3i;
            int4v ivB = {fB0, fB1, fB2, fB3};
            short8 bfB = __builtin_bit_cast(short8, ivB);
            f32x16 z = zero16();
            f32x16 dgB = __builtin_amdgcn_mfma_f32_32x32x16_bf16(wg, bfB, z, 0, 0, 0);
            f32x16 daB = __builtin_amdgcn_mfma_f32_32x32x16_bf16(wa, bfB, z, 0, 0, 0);
            float b0=0.f,b1=0.f,b2=0.f;
            #pragma unroll
            for (int r = 0; r < 8; r++){
                b0 += fmaxf(dgB[r],   nbg[r])   * g2g[r];
                b1 += fmaxf(dgB[r+8], nbg[r+8]) * g2g[r+8];
                b2 += fmaxf(daB[r],   nba[r])   * g2a[r];
            }
            accB = (b0 + b1) + b2;
        }
        accA += __shfl_xor(accA, 32);
        accB += __shfl_xor(accB, 32);

        float res = (lane < 32) ? accA : accB;   // this lane's pair = m0+lane
        acc_lds[0][nrow][lane] += msk*(res + cb);
    }
    __syncthreads();

    // ---------- phase 3: sum K-partials + diag + scale + coalesced store ----------
    {
        #pragma unroll
        for (int j = 0; j < 8; j++){
            int flat = tid + j*256;          // 0..2047
            int row = flat >> 6, col = flat & 63;
            float v = acc_lds[0][row][col] + acc_lds[1][row][col];
            int n = n0 + row, m = m0 + col;
            if (m == n) v += dv[b*512 + n];
            S[((size_t)b*512 + n)*512 + m] = v * ls;
        }
    }
}

extern "C" void kernel_launch(void* const* d_in, const int* in_sizes, int n_in,
                              void* d_out, int out_size, void* d_ws, size_t ws_size,
                              hipStream_t stream){
    const float* feats = (const float*)d_in[0];
    const float* xy    = (const float*)d_in[1];
    const float* Wq    = (const float*)d_in[2];
    const float* Wk    = (const float*)d_in[3];
    const float* Wpi   = (const float*)d_in[4];
    const float* bpi   = (const float*)d_in[5];
    const float* Wpj   = (const float*)d_in[6];
    const float* bpj   = (const float*)d_in[7];
    const float* gW1   = (const float*)d_in[8];
    const float* gb1   = (const float*)d_in[9];
    const float* gW2   = (const float*)d_in[10];
    const float* gb2   = (const float*)d_in[11];
    const float* aW1   = (const float*)d_in[12];
    const float* ab1   = (const float*)d_in[13];
    const float* aW2   = (const float*)d_in[14];
    const float* ab2   = (const float*)d_in[15];
    const float* dW    = (const float*)d_in[16];
    const float* db    = (const float*)d_in[17];
    const float* a_pair= (const float*)d_in[18];
    const float* a_geom= (const float*)d_in[19];
    const float* a_ang = (const float*)d_in[20];
    const float* lsc   = (const float*)d_in[21];

    float* S = (float*)d_out;
    char* wsb = (char*)d_ws;
    unsigned short* xb = (unsigned short*)wsb;                    // 4096*256*2 = 2,097,152 B
    unsigned short* WT = (unsigned short*)(wsb + 2097152);        // 448*256*2  =   229,376 B
    unsigned short* Ub = (unsigned short*)(wsb + 2326528);        // 4096*224*2 = 1,835,008 B
    unsigned short* Vb = (unsigned short*)(wsb + 4161536);        // 1,835,008 B
    float* bcat = (float*)(wsb + 5996544);                        // 448*4
    float* dv   = (float*)(wsb + 5998336);                        // 4096*4
    // total ~6.0 MB of d_ws

    k_prep <<<4544, 256, 0, stream>>>(feats, Wq, Wk, Wpi, bpi, Wpj, bpj, dW, db, a_pair,
                                      xb, WT, bcat);
    k_uv   <<<dim3(7,64), 256, 0, stream>>>(xb, WT, bcat, Ub, Vb, dv);
    k_gp   <<<dim3(8,16,8), 256, 0, stream>>>(Ub, Vb, xy, gW1, gb1, gW2, gb2,
                                              aW1, ab1, aW2, ab2, dv,
                                              a_geom, a_ang, lsc, S);
}

// Round 22
// 48.533 us; speedup vs baseline: 1.7719x; 1.7719x over previous
//
#include <hip/hip_runtime.h>
#include <math.h>

// ScoreNet: B=8, NV=512, C=256, H=6, R=32, PAIR_H=16, RBF_K=8
// R22: REVERT to R20 (best: 48.88 us). R21's (256,4)+sequential-chunk spilled
//   (FETCH 158MB+, 73us) — unified VGPR+AGPR footprint > 128 cap; occupancy
//   lever conclusively dead at 3 blocks/CU. R20 = fused k_gp with 32-row
//   tile, K-split phase1, dedup'd pair features, zero-work-free reduce.

#define UK 224

typedef __attribute__((ext_vector_type(8)))  short short8;
typedef __attribute__((ext_vector_type(16))) float f32x16;
typedef __attribute__((ext_vector_type(4)))  int   int4v;

__device__ __forceinline__ float sigmoidf_(float x){ return 1.0f/(1.0f + __expf(-x)); }
__device__ __forceinline__ unsigned f2bf(float x){
    unsigned u = __builtin_bit_cast(unsigned, x);
    return (u + 0x7fffu + ((u>>16)&1u)) >> 16;       // RNE f32->bf16
}
__device__ __forceinline__ unsigned pk2(float lo, float hi){
    unsigned r;
    asm("v_cvt_pk_bf16_f32 %0, %1, %2" : "=v"(r) : "v"(lo), "v"(hi));
    return r;
}
__device__ __forceinline__ f32x16 zero16(){
    f32x16 z;
    #pragma unroll
    for (int i = 0; i < 16; i++) z[i] = 0.f;
    return z;
}

// merged: blocks <4096 pool feats -> bf16 xb; blocks >=4096 pack WT (transposed, bf16) + bcat
__global__ __launch_bounds__(256) void k_prep(const float* __restrict__ feats,
        const float* __restrict__ Wq, const float* __restrict__ Wk,
        const float* __restrict__ Wpi, const float* __restrict__ bpi,
        const float* __restrict__ Wpj, const float* __restrict__ bpj,
        const float* __restrict__ dW, const float* __restrict__ db,
        const float* __restrict__ a_pair,
        unsigned short* __restrict__ xb, unsigned short* __restrict__ WT,
        float* __restrict__ bcat){
    int blk = blockIdx.x, tid = threadIdx.x;
    if (blk < 4096){
        int b = blk >> 9, n = blk & 511;
        size_t base = ((size_t)(b*1025 + 1 + 2*n))*256 + tid;
        float v = 0.5f*(feats[base] + feats[base+256]);
        xb[(size_t)blk*256 + tid] = (unsigned short)f2bf(v);
    } else {
        int col = blk - 4096;    // 0..447
        int c   = tid;           // k index 0..255
        const float invSqrtR = 0.17677669529663687f; // 1/sqrt(32)
        float sp = 1.5f*sigmoidf_(a_pair[0]);
        float v;
        if      (col < 192)  v = Wq[c*192 + col]*invSqrtR;
        else if (col < 208)  v = sp*Wpi[c*16 + (col-192)];
        else if (col < 400)  v = Wk[c*192 + (col-208)];
        else if (col < 416)  v = Wpj[c*16 + (col-400)];
        else if (col == 416) v = dW[c];
        else v = 0.f;
        WT[col*256 + c] = (unsigned short)f2bf(v);
        if (tid == 0){
            float bv = 0.f;
            if      (col >= 192 && col < 208) bv = sp*bpi[col-192];
            else if (col >= 400 && col < 416) bv = bpj[col-400];
            else if (col == 416)              bv = db[0];
            bcat[col] = bv;
        }
    }
}

// xb[4096][256] @ WT^T -> routed to Ub/Vb (bf16, [4096][224], zero-padded) + dv
__global__ __launch_bounds__(256) void k_uv(const unsigned short* __restrict__ xb,
        const unsigned short* __restrict__ WT, const float* __restrict__ bcat,
        unsigned short* __restrict__ Ub, unsigned short* __restrict__ Vb,
        float* __restrict__ dv){
    int tid = threadIdx.x;
    int lane = tid & 63, l31 = lane & 31, hf = lane >> 5;
    int w = tid >> 6, wr = w >> 1, wc = w & 1;
    int c0 = blockIdx.x*64, r0 = blockIdx.y*64;
    const unsigned short* ap = xb + (size_t)(r0 + wr*32 + l31)*256 + 8*hf;
    const unsigned short* bp = WT + (size_t)(c0 + wc*32 + l31)*256 + 8*hf;
    f32x16 acc = zero16();
    #pragma unroll 4
    for (int k0 = 0; k0 < 256; k0 += 16){
        short8 a  = *(const short8*)(ap + k0);
        short8 bb = *(const short8*)(bp + k0);
        acc = __builtin_amdgcn_mfma_f32_32x32x16_bf16(a, bb, acc, 0, 0, 0);
    }
    int col = c0 + wc*32 + l31;          // uniform per lane across all 16 accs
    int rb  = r0 + wr*32 + 4*hf;
    float bc = bcat[col];
    #pragma unroll
    for (int r = 0; r < 16; r++){
        int row = rb + (r&3) + 8*(r>>2);
        float v = acc[r] + bc;
        size_t ui = (size_t)row*UK;
        if (col < 208){
            if (col >= 192) v = fmaxf(v, 0.f);        // a_i relu
            Ub[ui + col] = (unsigned short)f2bf(v);
        } else if (col < 224){
            Vb[ui + col-208] = (unsigned short)f2bf(v);
            Ub[ui + col] = 0;                          // Ub K-pad
        } else if (col < 416){
            if (col >= 400) v = fmaxf(v, 0.f);        // b_j relu
            Vb[ui + col-208] = (unsigned short)f2bf(v);
        } else if (col == 416){
            dv[row] = v;
            Vb[ui + 208] = 0;                          // Vb K-pad
        } else if (col < 432){
            Vb[ui + col-208] = 0;                      // Vb K-pad (cols 417..431 are zero-cols)
        }
        // col >= 432: dead padding, skip
    }
}

// FUSED: S_lin (bf16 MFMA, K-split) + pair MLPs + diag + logit scale
// tile: 32 n-rows x 64 m-cols; grid dim3(8,16,8)
__global__ __launch_bounds__(256, 3) void k_gp(const unsigned short* __restrict__ Ub,
        const unsigned short* __restrict__ Vb, const float* __restrict__ xy,
        const float* __restrict__ gW1, const float* __restrict__ gb1,
        const float* __restrict__ gW2, const float* __restrict__ gb2,
        const float* __restrict__ aW1, const float* __restrict__ ab1,
        const float* __restrict__ aW2, const float* __restrict__ ab2,
        const float* __restrict__ dv,
        const float* __restrict__ a_geom, const float* __restrict__ a_ang,
        const float* __restrict__ lsc,
        float* __restrict__ S){
    __shared__ float acc_lds[2][32][64];   // two K-partials, 16 KB
    int tid = threadIdx.x;
    int lane = tid & 63, l31 = lane & 31, hf = lane >> 5;
    int w = tid >> 6, wr = w >> 1, wc = w & 1;   // wr = K-half, wc = m-half
    int b = blockIdx.z;
    int m0 = blockIdx.x*64, n0 = blockIdx.y*32;

    // ---------- phase 1: GEMM tile (K split across wave pairs) ----------
    {
        const unsigned short* ap = Ub + (size_t)(b*512 + n0 + l31)*UK + wr*112 + 8*hf;
        const unsigned short* bp = Vb + (size_t)(b*512 + m0 + wc*32 + l31)*UK + wr*112 + 8*hf;
        f32x16 acc = zero16();
        #pragma unroll
        for (int t = 0; t < 7; t++){
            short8 a  = *(const short8*)(ap + t*16);
            short8 bb = *(const short8*)(bp + t*16);
            acc = __builtin_amdgcn_mfma_f32_32x32x16_bf16(a, bb, acc, 0, 0, 0);
        }
        int colL = wc*32 + l31;
        #pragma unroll
        for (int r = 0; r < 16; r++)
            acc_lds[wr][(r&3) + 8*(r>>2) + 4*hf][colL] = acc[r];
    }
    __syncthreads();

    // ---------- pair-MLP setup (weights/tables) ----------
    float sg = 1.5f*sigmoidf_(a_geom[0]);
    float sa = 1.5f*sigmoidf_(a_ang[0]);
    float ls = 0.5f + 2.5f*sigmoidf_(lsc[0]);

    short8 wg, wa;
    #pragma unroll
    for (int j = 0; j < 8; j++){
        int f = hf*8 + j;
        float vg = (f < 12) ? gW1[f*32 + l31] : 0.f;
        float va = (f >= 10 && l31 < 16) ? aW1[(f-10)*16 + l31] : 0.f;
        wg[j] = (short)f2bf(vg);
        wa[j] = (short)f2bf(va);
    }
    // geom tables: all 16 regs; angle tables: only r=0..7 have h<16
    float nbg[16], g2g[16], nba[8], g2a[8];
    float bsum = 0.f;
    #pragma unroll
    for (int r = 0; r < 16; r++){
        int h = (r&3) + 8*(r>>2) + 4*hf;
        float bg  = gb1[h];
        float wg2 = sg*gW2[h];
        nbg[r] = -bg; g2g[r] = wg2; bsum += bg*wg2;
        if (r < 8){   // h<16 exactly when r<8 (both halves)
            float ba  = ab1[h];
            float wa2 = sa*aW2[h];
            nba[r] = -ba; g2a[r] = wa2; bsum += ba*wa2;
        }
    }
    bsum += __shfl_xor(bsum, 32);
    float cb = sg*gb2[0] + sa*ab2[0] + bsum;

    const float GAMMA = 12.2499985f;    // 1/(2*spacing^2 + 1e-8)
    const float TWOGD = 4.9497469f;     // 2*GAMMA*spacing
    const float* xyb = xy + (size_t)b*1024;

    // ---------- phase 2: pair MLPs for 8 tile rows per wave ----------
    int m_w = m0 + lane;                // this lane's own pair column (dedup)
    float2 pmv = *(const float2*)(xyb + 2*m_w);
    float ym = pmv.x, xm = pmv.y;
    bool padm = (fabsf(ym) < 1e-9f) && (fabsf(xm) < 1e-9f);

    for (int i = 0; i < 8; i++){
        int nrow = (w << 3) + i;        // tile-local row, wave-uniform
        int nn = n0 + nrow;
        float yn = xyb[2*nn], xn = xyb[2*nn+1];
        bool padn = (fabsf(yn) < 1e-9f) && (fabsf(xn) < 1e-9f);
        float msk = (padn || padm) ? 0.f : 1.f;

        float dy = yn - ym, dx = xn - xm;
        float r2 = dy*dy + dx*dx;
        float re = sqrtf(r2 + 1e-8f);
        float c1, s1;
        if (r2 > 0.f){ float inv = rsqrtf(r2); c1 = dx*inv; s1 = dy*inv; }
        else { c1 = 1.f; s1 = 0.f; }    // atan2(0,0)=0
        float c2 = c1*c1 - s1*s1, s2 = 2.f*c1*s1;
        float c4 = c2*c2 - s2*s2, s4 = 2.f*c2*s2;
        float e0 = __expf(-GAMMA*(r2 + 1e-8f));
        float E  = __expf(TWOGD*re);
        float u  = e0;
        float p0 = u;
        u *= E; float p1 = 0.60653066f*u;
        u *= E; float p2 = 0.13533528f*u;
        u *= E; float p3 = 0.011108997f*u;
        u *= E; float p4 = 3.3546263e-4f*u;
        u *= E; float p5 = 3.7266532e-6f*u;
        u *= E; float p6 = 1.5229979e-8f*u;
        u *= E; float p7 = 2.2897348e-11f*u;
        unsigned pk0 = pk2(dy, dx), pk1 = pk2(p0, p1), pk2_ = pk2(p2, p3), pk3 = pk2(p4, p5);
        unsigned pk4 = pk2(p6, p7), pk5 = pk2(c1, s1), pk6 = pk2(c2, s2), pk7 = pk2(c4, s4);

        // exchange partner k-halves (selection evaluated in SOURCE lane)
        int s0 = __shfl_xor((int)(hf ? pk0 : pk4), 32);
        int s1i= __shfl_xor((int)(hf ? pk1 : pk5), 32);
        int s2i= __shfl_xor((int)(hf ? pk2_: pk6), 32);
        int s3i= __shfl_xor((int)(hf ? pk3 : pk7), 32);

        int fA0 = hf ? s0 : (int)pk0, fA1 = hf ? s1i : (int)pk1;
        int fA2 = hf ? s2i : (int)pk2_, fA3 = hf ? s3i : (int)pk3;
        int fB0 = hf ? (int)pk4 : s0,  fB1 = hf ? (int)pk5 : s1i;
        int fB2 = hf ? (int)pk6 : s2i, fB3 = hf ? (int)pk7 : s3i;
        int4v ivA = {fA0, fA1, fA2, fA3};
        int4v ivB = {fB0, fB1, fB2, fB3};
        short8 bfA = __builtin_bit_cast(short8, ivA);
        short8 bfB = __builtin_bit_cast(short8, ivB);

        f32x16 z = zero16();
        f32x16 dgA = __builtin_amdgcn_mfma_f32_32x32x16_bf16(wg, bfA, z, 0, 0, 0);
        f32x16 dgB = __builtin_amdgcn_mfma_f32_32x32x16_bf16(wg, bfB, z, 0, 0, 0);
        f32x16 daA = __builtin_amdgcn_mfma_f32_32x32x16_bf16(wa, bfA, z, 0, 0, 0);
        f32x16 daB = __builtin_amdgcn_mfma_f32_32x32x16_bf16(wa, bfB, z, 0, 0, 0);

        // tree reduce: geom 16 regs (2 chains each), angle only r=0..7 (h<16)
        float a0=0.f,a1=0.f,a2=0.f,b0=0.f,b1=0.f,b2=0.f;
        #pragma unroll
        for (int r = 0; r < 8; r++){
            a0 += fmaxf(dgA[r],   nbg[r])   * g2g[r];
            a1 += fmaxf(dgA[r+8], nbg[r+8]) * g2g[r+8];
            b0 += fmaxf(dgB[r],   nbg[r])   * g2g[r];
            b1 += fmaxf(dgB[r+8], nbg[r+8]) * g2g[r+8];
            a2 += fmaxf(daA[r],   nba[r])   * g2a[r];
            b2 += fmaxf(daB[r],   nba[r])   * g2a[r];
        }
        float accA = (a0 + a1) + a2;
        float accB = (b0 + b1) + b2;
        accA += __shfl_xor(accA, 32);
        accB += __shfl_xor(accB, 32);

        float res = (lane < 32) ? accA : accB;   // this lane's pair = m0+lane
        acc_lds[0][nrow][lane] += msk*(res + cb);
    }
    __syncthreads();

    // ---------- phase 3: sum K-partials + diag + scale + coalesced store ----------
    {
        #pragma unroll
        for (int j = 0; j < 8; j++){
            int flat = tid + j*256;          // 0..2047
            int row = flat >> 6, col = flat & 63;
            float v = acc_lds[0][row][col] + acc_lds[1][row][col];
            int n = n0 + row, m = m0 + col;
            if (m == n) v += dv[b*512 + n];
            S[((size_t)b*512 + n)*512 + m] = v * ls;
        }
    }
}

extern "C" void kernel_launch(void* const* d_in, const int* in_sizes, int n_in,
                              void* d_out, int out_size, void* d_ws, size_t ws_size,
                              hipStream_t stream){
    const float* feats = (const float*)d_in[0];
    const float* xy    = (const float*)d_in[1];
    const float* Wq    = (const float*)d_in[2];
    const float* Wk    = (const float*)d_in[3];
    const float* Wpi   = (const float*)d_in[4];
    const float* bpi   = (const float*)d_in[5];
    const float* Wpj   = (const float*)d_in[6];
    const float* bpj   = (const float*)d_in[7];
    const float* gW1   = (const float*)d_in[8];
    const float* gb1   = (const float*)d_in[9];
    const float* gW2   = (const float*)d_in[10];
    const float* gb2   = (const float*)d_in[11];
    const float* aW1   = (const float*)d_in[12];
    const float* ab1   = (const float*)d_in[13];
    const float* aW2   = (const float*)d_in[14];
    const float* ab2   = (const float*)d_in[15];
    const float* dW    = (const float*)d_in[16];
    const float* db    = (const float*)d_in[17];
    const float* a_pair= (const float*)d_in[18];
    const float* a_geom= (const float*)d_in[19];
    const float* a_ang = (const float*)d_in[20];
    const float* lsc   = (const float*)d_in[21];

    float* S = (float*)d_out;
    char* wsb = (char*)d_ws;
    unsigned short* xb = (unsigned short*)wsb;                    // 4096*256*2 = 2,097,152 B
    unsigned short* WT = (unsigned short*)(wsb + 2097152);        // 448*256*2  =   229,376 B
    unsigned short* Ub = (unsigned short*)(wsb + 2326528);        // 4096*224*2 = 1,835,008 B
    unsigned short* Vb = (unsigned short*)(wsb + 4161536);        // 1,835,008 B
    float* bcat = (float*)(wsb + 5996544);                        // 448*4
    float* dv   = (float*)(wsb + 5998336);                        // 4096*4
    // total ~6.0 MB of d_ws

    k_prep <<<4544, 256, 0, stream>>>(feats, Wq, Wk, Wpi, bpi, Wpj, bpj, dW, db, a_pair,
                                      xb, WT, bcat);
    k_uv   <<<dim3(7,64), 256, 0, stream>>>(xb, WT, bcat, Ub, Vb, dv);
    k_gp   <<<dim3(8,16,8), 256, 0, stream>>>(Ub, Vb, xy, gW1, gb1, gW2, gb2,
                                              aW1, ab1, aW2, ab2, dv,
                                              a_geom, a_ang, lsc, S);
}